// Round 1
// baseline (311.520 us; speedup 1.0000x reference)
//
#include <hip/hip_runtime.h>
#include <hip/hip_bf16.h>
#include <math.h>

// Problem constants
#define BATCH 1024
#define NREAL 784
#define NPAD  896      // 7*128, zero-padded graph dim
#define C1D   32
#define C2D   32
#define HDIM  512
#define NCLS  10
#define KFC   25088    // 784*32

#define KS_G1 7        // split-K for G1 (K=896 -> 128/slice, 4 iters, EVEN)
#define KS_FC 14       // split-K for fc1 (K=25088 -> 1792/slice, 56 iters, EVEN)

// GEMM tile (128x128 kernel, used for G1/G4)
#define BM 128
#define BN 128
#define BK 32

using bf16x8  = __attribute__((ext_vector_type(8))) __bf16;
using floatx4 = __attribute__((ext_vector_type(4))) float;

__device__ __forceinline__ float elu_f(float t) {
    return t > 0.f ? t : (__expf(t) - 1.f);
}

// LDS-only barrier: waits ds ops but leaves global loads (vmcnt) in flight.
__device__ __forceinline__ void wg_barrier_lds() {
    asm volatile("s_waitcnt lgkmcnt(0)\n\ts_barrier" ::: "memory");
}

// raw barrier (no waitcnt) — used by the phased 256^2 kernel
__device__ __forceinline__ void bar() {
    asm volatile("s_barrier" ::: "memory");
}

// lgkm drain + scheduler fence (rule #18: pin MFMAs after the wait)
__device__ __forceinline__ void lgkm0_fence() {
    asm volatile("s_waitcnt lgkmcnt(0)" ::: "memory");
    __builtin_amdgcn_sched_barrier(0);
}

// async global->LDS, 16B per lane; LDS dest must be wave-uniform base
__device__ __forceinline__ void gload_lds16(const __hip_bfloat16* g, __hip_bfloat16* l) {
    __builtin_amdgcn_global_load_lds(
        (const __attribute__((address_space(1))) void*)g,
        (__attribute__((address_space(3))) void*)l, 16, 0, 0);
}

// ---------------------------------------------------------------------------
// BT-GEMM, register-staged pipeline + XOR-swizzled LDS layout (G1, G4).
// (unchanged from previous round; see comments there)
// ---------------------------------------------------------------------------
template<int MODE>
__launch_bounds__(256)
__global__ void gemm_bt(const __hip_bfloat16* __restrict__ A, int lda,
                        const __hip_bfloat16* __restrict__ Bm, int ldb,
                        int kIters, int kPerZ, size_t sliceStride,
                        float* __restrict__ outF, int ldc,
                        __hip_bfloat16* __restrict__ outH,
                        const float* __restrict__ bias)
{
    __shared__ __align__(16) __hip_bfloat16 As[2][BM * BK];
    __shared__ __align__(16) __hip_bfloat16 Bs[2][BN * BK];

    const int tid  = threadIdx.x;
    const int lane = tid & 63;
    const int wave = tid >> 6;
    const int wi = wave >> 1, wj = wave & 1;

    const int m0 = blockIdx.y * BM;
    const int n0 = blockIdx.x * BN;
    const int kBase = blockIdx.z * kPerZ;

    const int rowInChunk = lane >> 2;
    const int kOff8 = (lane & 3) * 8;

    const __hip_bfloat16* aSrc0 = A  + (size_t)(m0 + (wave * 2 + 0) * 16 + rowInChunk) * lda + kBase + kOff8;
    const __hip_bfloat16* aSrc1 = A  + (size_t)(m0 + (wave * 2 + 1) * 16 + rowInChunk) * lda + kBase + kOff8;
    const __hip_bfloat16* bSrc0 = Bm + (size_t)(n0 + (wave * 2 + 0) * 16 + rowInChunk) * ldb + kBase + kOff8;
    const __hip_bfloat16* bSrc1 = Bm + (size_t)(n0 + (wave * 2 + 1) * 16 + rowInChunk) * ldb + kBase + kOff8;

    const int wSlot = (((lane & 3) + ((lane >> 3) & 3)) & 3) * 8;
    const int ldsW0 = (wave * 2 + 0) * 512 + rowInChunk * 32 + wSlot;
    const int ldsW1 = ldsW0 + 512;

    const int rSlot = ((((lane >> 4) + (((lane & 15) >> 1) & 3)) & 3)) * 8;
    const int rRow  = lane & 15;

    floatx4 acc[4][4];
    const floatx4 zero4 = {0.f, 0.f, 0.f, 0.f};
    #pragma unroll
    for (int i = 0; i < 4; i++)
        #pragma unroll
        for (int j = 0; j < 4; j++) acc[i][j] = zero4;

    int4 aA0, aA1, bA0, bA1;
    int4 aB0, aB1, bB0, bB1;

    aA0 = *(const int4*)aSrc0; aA1 = *(const int4*)aSrc1;
    bA0 = *(const int4*)bSrc0; bA1 = *(const int4*)bSrc1;
    aSrc0 += BK; aSrc1 += BK; bSrc0 += BK; bSrc1 += BK;
    aB0 = *(const int4*)aSrc0; aB1 = *(const int4*)aSrc1;
    bB0 = *(const int4*)bSrc0; bB1 = *(const int4*)bSrc1;
    aSrc0 += BK; aSrc1 += BK; bSrc0 += BK; bSrc1 += BK;

    *(int4*)(&As[0][ldsW0]) = aA0;
    *(int4*)(&As[0][ldsW1]) = aA1;
    *(int4*)(&Bs[0][ldsW0]) = bA0;
    *(int4*)(&Bs[0][ldsW1]) = bA1;
    wg_barrier_lds();

    for (int kt = 0; kt < kIters; kt += 2) {
        const bool more = (kt + 2 < kIters);

        {
            bf16x8 af[4], bfr[4];
            #pragma unroll
            for (int mi = 0; mi < 4; mi++)
                af[mi] = *(const bf16x8*)(&As[0][(wi * 64 + mi * 16 + rRow) * BK + rSlot]);
            #pragma unroll
            for (int nj = 0; nj < 4; nj++)
                bfr[nj] = *(const bf16x8*)(&Bs[0][(wj * 64 + nj * 16 + rRow) * BK + rSlot]);

            if (more) {
                aA0 = *(const int4*)aSrc0; aA1 = *(const int4*)aSrc1;
                bA0 = *(const int4*)bSrc0; bA1 = *(const int4*)bSrc1;
                aSrc0 += BK; aSrc1 += BK; bSrc0 += BK; bSrc1 += BK;
            }
            *(int4*)(&As[1][ldsW0]) = aB0;
            *(int4*)(&As[1][ldsW1]) = aB1;
            *(int4*)(&Bs[1][ldsW0]) = bB0;
            *(int4*)(&Bs[1][ldsW1]) = bB1;

            #pragma unroll
            for (int mi = 0; mi < 4; mi++)
                #pragma unroll
                for (int nj = 0; nj < 4; nj++)
                    acc[mi][nj] = __builtin_amdgcn_mfma_f32_16x16x32_bf16(af[mi], bfr[nj], acc[mi][nj], 0, 0, 0);

            wg_barrier_lds();
        }

        {
            bf16x8 af[4], bfr[4];
            #pragma unroll
            for (int mi = 0; mi < 4; mi++)
                af[mi] = *(const bf16x8*)(&As[1][(wi * 64 + mi * 16 + rRow) * BK + rSlot]);
            #pragma unroll
            for (int nj = 0; nj < 4; nj++)
                bfr[nj] = *(const bf16x8*)(&Bs[1][(wj * 64 + nj * 16 + rRow) * BK + rSlot]);

            if (more) {
                aB0 = *(const int4*)aSrc0; aB1 = *(const int4*)aSrc1;
                bB0 = *(const int4*)bSrc0; bB1 = *(const int4*)bSrc1;
                aSrc0 += BK; aSrc1 += BK; bSrc0 += BK; bSrc1 += BK;
                *(int4*)(&As[0][ldsW0]) = aA0;
                *(int4*)(&As[0][ldsW1]) = aA1;
                *(int4*)(&Bs[0][ldsW0]) = bA0;
                *(int4*)(&Bs[0][ldsW1]) = bA1;
            }

            #pragma unroll
            for (int mi = 0; mi < 4; mi++)
                #pragma unroll
                for (int nj = 0; nj < 4; nj++)
                    acc[mi][nj] = __builtin_amdgcn_mfma_f32_16x16x32_bf16(af[mi], bfr[nj], acc[mi][nj], 0, 0, 0);

            wg_barrier_lds();
        }
    }

    #pragma unroll
    for (int mi = 0; mi < 4; mi++) {
        #pragma unroll
        for (int nj = 0; nj < 4; nj++) {
            #pragma unroll
            for (int r = 0; r < 4; r++) {
                const int row = m0 + wi * 64 + mi * 16 + (lane >> 4) * 4 + r;
                const int col = n0 + wj * 64 + nj * 16 + (lane & 15);
                const float v = acc[mi][nj][r];
                if (MODE == 1) {
                    if (row < NREAL) {
                        const int c = col & 31, b = col >> 5;
                        const float t = elu_f(v + bias[c]);
                        outH[(size_t)b * KFC + row * 32 + c] = __float2bfloat16(t);
                    }
                } else {
                    outF[(size_t)blockIdx.z * sliceStride + (size_t)row * ldc + col] = v;
                }
            }
        }
    }
}

// ---------------------------------------------------------------------------
// G3: 256x256 phased GEMM (m201-style 8-phase schedule, plain HIP).
//   C[n][j] = sum_m Abf[n][m] * Tt[j][m],  n tile: blockIdx.y*256 (M=1024,
//   rows >=896 source-clamped -> garbage, store-masked), j tile:
//   blockIdx.x*256 (N=32768), K=896 = 14 tiles of BK=64.
//
// 512 threads = 8 waves (2M x 4N); per-wave output 128x64 = acc[8][4].
// LDS 128 KiB: As/Bs [2][256*64] bf16, rotation swizzle: element (row,k)
// at row*64 + ((k>>3 + (row&7))&7)*8 + (k&7).  Reads (ds_read_b128,
// lanes 0-15 same k-group, rows 0-15) are 2-way = free (m136).
// Staging: global_load_lds dwordx4, LINEAR LDS dest (wave-uniform base +
// lane*16B), PRE-SWIZZLED per-lane global source (rule #21).  Each wave
// stages 4 x 1KB granules (8 rows) per matrix per tile.
//
// Per K-tile: 4 quadrant phases (mh,nh), each exactly 16 MFMA 16x16x32.
// Phase: {12 ds_read_b128; [stage issues]; barrier; lgkmcnt(0)+sched_barrier;
//         setprio(1); 16 MFMA; setprio(0); barrier}.
// Counted vmcnt: prologue stages tiles 0,1 then vmcnt(8); tiles 1..12 issue
// next tile's 8 loads in phases 0(A)/1(B); one vmcnt(0) per tile boundary
// (only current-tile loads in flight -> no over-drain).
// ---------------------------------------------------------------------------
#define KT_G3 14

#define G3_PHASE(MH, NH, PRE_BAR, ISS_A, ISS_B)                                   \
  {                                                                               \
    bf16x8 a0_[4], a1_[4], b0_[2], b1_[2];                                        \
    _Pragma("unroll")                                                             \
    for (int i_ = 0; i_ < 4; i_++) {                                              \
      const int ro_ = aRowOff + ((MH) * 4 + i_) * 1024;                           \
      a0_[i_] = *(const bf16x8*)(&As[cur][ro_ + koff0]);                          \
      a1_[i_] = *(const bf16x8*)(&As[cur][ro_ + koff1]);                          \
    }                                                                             \
    _Pragma("unroll")                                                             \
    for (int j_ = 0; j_ < 2; j_++) {                                              \
      const int ro_ = bRowOff + ((NH) * 2 + j_) * 1024;                           \
      b0_[j_] = *(const bf16x8*)(&Bs[cur][ro_ + koff0]);                          \
      b1_[j_] = *(const bf16x8*)(&Bs[cur][ro_ + koff1]);                          \
    }                                                                             \
    if (ISS_A) {                                                                  \
      _Pragma("unroll")                                                           \
      for (int j_ = 0; j_ < 4; j_++)                                              \
        gload_lds16(aSrc[j_] + kNext, &As[nb][(w4 + j_) * 512]);                  \
    }                                                                             \
    if (ISS_B) {                                                                  \
      _Pragma("unroll")                                                           \
      for (int j_ = 0; j_ < 4; j_++)                                              \
        gload_lds16(bSrc[j_] + kNext, &Bs[nb][(w4 + j_) * 512]);                  \
    }                                                                             \
    if (PRE_BAR) bar();                                                           \
    lgkm0_fence();                                                                \
    __builtin_amdgcn_s_setprio(1);                                                \
    _Pragma("unroll")                                                             \
    for (int j_ = 0; j_ < 2; j_++)                                                \
      _Pragma("unroll")                                                           \
      for (int i_ = 0; i_ < 4; i_++)                                              \
        acc[(MH) * 4 + i_][(NH) * 2 + j_] = __builtin_amdgcn_mfma_f32_16x16x32_bf16( \
            a0_[i_], b0_[j_], acc[(MH) * 4 + i_][(NH) * 2 + j_], 0, 0, 0);        \
    _Pragma("unroll")                                                             \
    for (int j_ = 0; j_ < 2; j_++)                                                \
      _Pragma("unroll")                                                           \
      for (int i_ = 0; i_ < 4; i_++)                                              \
        acc[(MH) * 4 + i_][(NH) * 2 + j_] = __builtin_amdgcn_mfma_f32_16x16x32_bf16( \
            a1_[i_], b1_[j_], acc[(MH) * 4 + i_][(NH) * 2 + j_], 0, 0, 0);        \
    __builtin_amdgcn_s_setprio(0);                                                \
    bar();                                                                        \
  }

__launch_bounds__(512)
__global__ void gemm256_g3(const __hip_bfloat16* __restrict__ Ag,   // Abf [896][896]
                           const __hip_bfloat16* __restrict__ Bg,   // Tt  [32768][896]
                           __hip_bfloat16* __restrict__ outH,       // h2f
                           const float* __restrict__ bias)          // b2 [32]
{
    __shared__ __align__(16) __hip_bfloat16 As[2][256 * 64];
    __shared__ __align__(16) __hip_bfloat16 Bs[2][256 * 64];

    const int tid  = threadIdx.x;
    const int lane = tid & 63;
    const int wave = tid >> 6;
    const int WM = wave >> 2, WN = wave & 3;
    const int w4 = wave * 4;

    const int mR = blockIdx.y * 256;    // output rows (Abf rows, clamped source)
    const int nR = blockIdx.x * 256;    // output cols (Tt rows)

    // ---- read-side constants ----
    const int rRow = lane & 15;
    const int gHi  = lane >> 4;              // 0..3
    const int rot  = lane & 7;               // == (read row) & 7
    const int koff0 = (((gHi + rot) & 7) << 3);
    const int koff1 = ((((4 + gHi) + rot) & 7) << 3);
    const int aRowOff = (WM * 128 + rRow) * 64;
    const int bRowOff = (WN * 64 + rRow) * 64;

    // ---- staging constants (pre-swizzled global source, linear LDS dest) ----
    // granule g = w4+j covers rows [g*8, g*8+8); lane covers (row=g*8+(lane>>3),
    // slot=lane&7); source k-group = (slot - row&7)&7 with row&7 == lane>>3.
    const int rowLoc = lane >> 3;
    const int gOff   = ((((lane & 7) - rowLoc) & 7) << 3);
    const __hip_bfloat16* aSrc[4];
    const __hip_bfloat16* bSrc[4];
    #pragma unroll
    for (int j = 0; j < 4; j++) {
        int ra = mR + (w4 + j) * 8 + rowLoc;
        if (ra > NPAD - 1) ra = NPAD - 1;     // clamp: garbage rows are store-masked
        aSrc[j] = Ag + (size_t)ra * NPAD + gOff;
        const int rb = nR + (w4 + j) * 8 + rowLoc;
        bSrc[j] = Bg + (size_t)rb * NPAD + gOff;
    }

    floatx4 acc[8][4];
    const floatx4 zero4 = {0.f, 0.f, 0.f, 0.f};
    #pragma unroll
    for (int i = 0; i < 8; i++)
        #pragma unroll
        for (int j = 0; j < 4; j++) acc[i][j] = zero4;

    // ---- prologue: stage tile 0 -> buf0, tile 1 -> buf1 ----
    #pragma unroll
    for (int j = 0; j < 4; j++) gload_lds16(aSrc[j],      &As[0][(w4 + j) * 512]);
    #pragma unroll
    for (int j = 0; j < 4; j++) gload_lds16(bSrc[j],      &Bs[0][(w4 + j) * 512]);
    #pragma unroll
    for (int j = 0; j < 4; j++) gload_lds16(aSrc[j] + 64, &As[1][(w4 + j) * 512]);
    #pragma unroll
    for (int j = 0; j < 4; j++) gload_lds16(bSrc[j] + 64, &Bs[1][(w4 + j) * 512]);
    asm volatile("s_waitcnt vmcnt(8)" ::: "memory");   // tile-0's 8 landed; tile-1 in flight
    bar();

    for (int t = 0; t < KT_G3; ++t) {
        const int cur = t & 1;
        const int nb  = cur ^ 1;
        const int kNext = (t + 1) * 64;
        const bool iss = (t >= 1) & (t < KT_G3 - 1);   // stage tile t+1 (tiles 2..13)

        if (t) {                                       // tile boundary: only this
            asm volatile("s_waitcnt vmcnt(0)" ::: "memory");  // tile's loads in flight
            bar();
        }
        G3_PHASE(0, 0, false, iss, false)
        G3_PHASE(0, 1, true,  false, iss)
        G3_PHASE(1, 0, true,  false, false)
        G3_PHASE(1, 1, true,  false, false)
    }

    // ---- epilogue: C/D layout col=lane&15, row=(lane>>4)*4+reg (m89/m91) ----
    #pragma unroll
    for (int mi = 0; mi < 8; mi++) {
        #pragma unroll
        for (int nj = 0; nj < 4; nj++) {
            #pragma unroll
            for (int r = 0; r < 4; r++) {
                const int row = mR + WM * 128 + mi * 16 + gHi * 4 + r;
                const int col = nR + WN * 64 + nj * 16 + rRow;
                if (row < NREAL) {
                    const int c = col & 31, b = col >> 5;
                    const float v = elu_f(acc[mi][nj][r] + bias[c]);
                    outH[(size_t)b * KFC + row * 32 + c] = __float2bfloat16(v);
                }
            }
        }
    }
}

// ---------------------------------------------------------------------------
// Conversions / padding
// ---------------------------------------------------------------------------
__global__ void convX(const float* __restrict__ x, __hip_bfloat16* __restrict__ Xbf) {
    const int idx = blockIdx.x * 256 + threadIdx.x;
    if (idx >= BATCH * NPAD) return;
    const int m = idx % NPAD, b = idx / NPAD;
    const float v = (m < NREAL) ? x[(size_t)b * NREAL + m] : 0.f;
    Xbf[idx] = __float2bfloat16(v);
}

__global__ void convA(const float* __restrict__ a, __hip_bfloat16* __restrict__ Abf) {
    const int idx = blockIdx.x * 256 + threadIdx.x;
    if (idx >= NPAD * NPAD) return;
    const int m = idx % NPAD, n = idx / NPAD;
    const float v = (m < NREAL && n < NREAL) ? a[(size_t)n * NREAL + m] : 0.f;
    Abf[idx] = __float2bfloat16(v);
}

// wf1 [25088][512] fp32 -> Wt [512][25088] bf16 (LDS tile transpose)
__global__ void convW(const float* __restrict__ wf1, __hip_bfloat16* __restrict__ Wt) {
    __shared__ float tile[32][33];
    const int k0 = blockIdx.x * 32, h0 = blockIdx.y * 32;
    const int tx = threadIdx.x, ty = threadIdx.y;  // (32,8)
    #pragma unroll
    for (int i = 0; i < 4; i++)
        tile[ty * 4 + i][tx] = wf1[(size_t)(k0 + ty * 4 + i) * HDIM + h0 + tx];
    __syncthreads();
    #pragma unroll
    for (int i = 0; i < 4; i++)
        Wt[(size_t)(h0 + ty * 4 + i) * KFC + k0 + tx] = __float2bfloat16(tile[tx][ty * 4 + i]);
}

// ---------------------------------------------------------------------------
// Layer-1 fused pointwise
// ---------------------------------------------------------------------------
__global__ void layer1_fuse(const float* __restrict__ Ypart,
                            const float* __restrict__ w1, const float* __restrict__ b1,
                            const float* __restrict__ w2,
                            __hip_bfloat16* __restrict__ Tt)
{
    __shared__ __align__(16) float sW2[C1D * C2D];
    __shared__ float sw1[C1D], sb1[C1D];
    const int tid = threadIdx.x;                 // 128 threads
    for (int i = tid; i < C1D * C2D; i += 128) sW2[i] = w2[i];
    if (tid < C1D) { sw1[tid] = w1[tid]; sb1[tid] = b1[tid]; }
    __syncthreads();

    const int m = blockIdx.x * 128 + tid;        // 0..895
    const int b = blockIdx.y;
    float y = 0.f;
    #pragma unroll
    for (int z = 0; z < KS_G1; z++)
        y += Ypart[(size_t)z * (BATCH * NPAD) + (size_t)b * NPAD + m];

    float h[C1D];
    #pragma unroll
    for (int c1 = 0; c1 < C1D; c1++) h[c1] = elu_f(y * sw1[c1] + sb1[c1]);

    float4 t4[8];
    #pragma unroll
    for (int q = 0; q < 8; q++) t4[q] = make_float4(0.f, 0.f, 0.f, 0.f);
    #pragma unroll
    for (int c1 = 0; c1 < C1D; c1++) {
        const float hv = h[c1];
        const float4* row = (const float4*)(sW2 + c1 * C2D);
        #pragma unroll
        for (int q = 0; q < 8; q++) {
            const float4 w = row[q];
            t4[q].x += hv * w.x; t4[q].y += hv * w.y;
            t4[q].z += hv * w.z; t4[q].w += hv * w.w;
        }
    }
    const float* tf = (const float*)t4;
    #pragma unroll
    for (int c = 0; c < C2D; c++)
        Tt[((size_t)(b * 32 + c)) * NPAD + m] = __float2bfloat16(tf[c]);
}

// ---------------------------------------------------------------------------
// fc1 reduce + relu + fc2 + softmax, fused.
// ---------------------------------------------------------------------------
__global__ void fc2_softmax(const float* __restrict__ part, const float* __restrict__ bf1,
                            const float* __restrict__ wf2, const float* __restrict__ bf2,
                            float* __restrict__ out)
{
    __shared__ float sW[HDIM * NCLS];
    __shared__ float sb[NCLS];
    const int tid = threadIdx.x;                 // 256
    for (int i = tid; i < HDIM * NCLS; i += 256) sW[i] = wf2[i];
    if (tid < NCLS) sb[tid] = bf2[tid];
    __syncthreads();

    const int lane = tid & 63, wave = tid >> 6;
    const int b = blockIdx.x * 4 + wave;

    float acc[NCLS];
    #pragma unroll
    for (int c = 0; c < NCLS; c++) acc[c] = 0.f;
    #pragma unroll
    for (int q = 0; q < 8; q++) {
        const int h = q * 64 + lane;
        float hv = bf1[h];
        #pragma unroll
        for (int z = 0; z < KS_FC; z++)
            hv += part[(size_t)z * (BATCH * HDIM) + (size_t)b * HDIM + h];
        hv = hv > 0.f ? hv : 0.f;
        #pragma unroll
        for (int c = 0; c < NCLS; c++) acc[c] += hv * sW[h * NCLS + c];
    }
    #pragma unroll
    for (int c = 0; c < NCLS; c++) {
        #pragma unroll
        for (int off = 32; off >= 1; off >>= 1) acc[c] += __shfl_down(acc[c], off);
    }
    if (lane == 0) {
        float mx = -1e30f;
        #pragma unroll
        for (int c = 0; c < NCLS; c++) { acc[c] += sb[c]; mx = fmaxf(mx, acc[c]); }
        float e[NCLS], s = 0.f;
        #pragma unroll
        for (int c = 0; c < NCLS; c++) { e[c] = __expf(acc[c] - mx); s += e[c]; }
        const float inv = 1.f / s;
        #pragma unroll
        for (int c = 0; c < NCLS; c++) out[(size_t)b * NCLS + c] = e[c] * inv;
    }
}

// ---------------------------------------------------------------------------
// Workspace layout (peak ~113.5 MB) — unchanged
//   h2f   [0,          51380224)  bf16 1024x25088  (written G3, read G4)
//     Ypart [0, 25690112) f32 7x1024x896 — overlay, dead before G3 writes h2f
//   Tt    [51380224,  110100480)  bf16 32768x896   (dead after G3)
//     Wt   [51380224, 77070336)   bf16 512x25088 — overlay after G3
//     part [77070336, 106430464)  f32 14x1024x512 — overlay after G3
//   Abf   [110100480, 111706112)  bf16 896x896
//   Xbf   [111706112, 113541120)  bf16 1024x896    (dead after G1)
// ---------------------------------------------------------------------------
extern "C" void kernel_launch(void* const* d_in, const int* in_sizes, int n_in,
                              void* d_out, int out_size, void* d_ws, size_t ws_size,
                              hipStream_t stream)
{
    const float* x   = (const float*)d_in[0];
    const float* a   = (const float*)d_in[1];
    const float* w1  = (const float*)d_in[2];
    const float* b1  = (const float*)d_in[3];
    const float* w2  = (const float*)d_in[4];
    const float* b2  = (const float*)d_in[5];
    const float* wf1 = (const float*)d_in[6];
    const float* bf1 = (const float*)d_in[7];
    const float* wf2 = (const float*)d_in[8];
    const float* bf2 = (const float*)d_in[9];
    float* out = (float*)d_out;

    char* ws = (char*)d_ws;
    __hip_bfloat16* h2f  = (__hip_bfloat16*)(ws + 0);
    float*          Ypart= (float*)(ws + 0);                  // overlay (pre-G3)
    __hip_bfloat16* Tt   = (__hip_bfloat16*)(ws + 51380224);
    __hip_bfloat16* Wt   = (__hip_bfloat16*)(ws + 51380224);  // overlay (post-G3)
    float*          part = (float*)(ws + 77070336);           // overlay (post-G3)
    __hip_bfloat16* Abf  = (__hip_bfloat16*)(ws + 110100480);
    __hip_bfloat16* Xbf  = (__hip_bfloat16*)(ws + 111706112);

    convX<<<(BATCH * NPAD + 255) / 256, 256, 0, stream>>>(x, Xbf);
    convA<<<(NPAD * NPAD + 255) / 256, 256, 0, stream>>>(a, Abf);

    // G1: Ypart[z][b][n] partials of sum_m Xbf[b][m]*Abf[n][m]
    gemm_bt<2><<<dim3(NPAD / BN, BATCH / BM, KS_G1), 256, 0, stream>>>(
        Xbf, NPAD, Abf, NPAD, (NPAD / KS_G1) / BK, NPAD / KS_G1,
        (size_t)BATCH * NPAD, Ypart, NPAD, nullptr, nullptr);

    // layer-1 pointwise + @W2, transposed store
    layer1_fuse<<<dim3(NPAD / 128, BATCH), 128, 0, stream>>>(Ypart, w1, b1, w2, Tt);

    // G3: h2 = elu(A @ T + b2) — 256^2 phased kernel
    //     grid: x = 128 j-tiles (Tt rows), y = 4 n-tiles (rows 896..1023 clamped+masked)
    gemm256_g3<<<dim3(BATCH * 32 / 256, 1024 / 256), 512, 0, stream>>>(Abf, Tt, h2f, b2);

    // transpose wf1 -> bf16 (into the now-dead Tt region)
    convW<<<dim3(KFC / 32, HDIM / 32), dim3(32, 8), 0, stream>>>(wf1, Wt);

    // G4: fc1 partials, split-K=14
    gemm_bt<2><<<dim3(HDIM / BN, BATCH / BM, KS_FC), 256, 0, stream>>>(
        h2f, KFC, Wt, KFC, (KFC / KS_FC) / BK, KFC / KS_FC,
        (size_t)BATCH * HDIM, part, HDIM, nullptr, nullptr);

    // fc1 reduce + relu + fc2 + softmax
    fc2_softmax<<<BATCH / 4, 256, 0, stream>>>(part, bf1, wf2, bf2, out);
}

// Round 2
// 280.124 us; speedup vs baseline: 1.1121x; 1.1121x over previous
//
#include <hip/hip_runtime.h>
#include <hip/hip_bf16.h>
#include <math.h>

// Problem constants
#define BATCH 1024
#define NREAL 784
#define NPAD  896      // 7*128, zero-padded graph dim
#define C1D   32
#define C2D   32
#define HDIM  512
#define NCLS  10
#define KFC   25088    // 784*32

#define KS_G1 7        // split-K for G1 (K=896 -> 128/slice, 4 iters, EVEN)
#define KS_FC 14       // split-K for fc1 (K=25088 -> 1792/slice, 56 iters, EVEN)

// GEMM tile (128x128 kernel, used for G1/G4)
#define BM 128
#define BN 128
#define BK 32

using bf16x8  = __attribute__((ext_vector_type(8))) __bf16;
using floatx4 = __attribute__((ext_vector_type(4))) float;

__device__ __forceinline__ float elu_f(float t) {
    return t > 0.f ? t : (__expf(t) - 1.f);
}

// LDS-only barrier: waits ds ops but leaves global loads (vmcnt) in flight.
__device__ __forceinline__ void wg_barrier_lds() {
    asm volatile("s_waitcnt lgkmcnt(0)\n\ts_barrier" ::: "memory");
}

// raw barrier (no waitcnt)
__device__ __forceinline__ void bar() {
    asm volatile("s_barrier" ::: "memory");
}

// lgkm drain + scheduler fence (rule #18: pin MFMAs after the wait)
__device__ __forceinline__ void lgkm0_fence() {
    asm volatile("s_waitcnt lgkmcnt(0)" ::: "memory");
    __builtin_amdgcn_sched_barrier(0);
}

// async global->LDS, 16B per lane; LDS dest is wave-uniform base + lane*16
__device__ __forceinline__ void gload_lds16(const __hip_bfloat16* g, __hip_bfloat16* l) {
    __builtin_amdgcn_global_load_lds(
        (const __attribute__((address_space(1))) void*)g,
        (__attribute__((address_space(3))) void*)l, 16, 0, 0);
}

// ---------------------------------------------------------------------------
// BT-GEMM, register-staged pipeline + XOR-swizzled LDS layout (G1, G4).
// (unchanged)
// ---------------------------------------------------------------------------
template<int MODE>
__launch_bounds__(256)
__global__ void gemm_bt(const __hip_bfloat16* __restrict__ A, int lda,
                        const __hip_bfloat16* __restrict__ Bm, int ldb,
                        int kIters, int kPerZ, size_t sliceStride,
                        float* __restrict__ outF, int ldc,
                        __hip_bfloat16* __restrict__ outH,
                        const float* __restrict__ bias)
{
    __shared__ __align__(16) __hip_bfloat16 As[2][BM * BK];
    __shared__ __align__(16) __hip_bfloat16 Bs[2][BN * BK];

    const int tid  = threadIdx.x;
    const int lane = tid & 63;
    const int wave = tid >> 6;
    const int wi = wave >> 1, wj = wave & 1;

    const int m0 = blockIdx.y * BM;
    const int n0 = blockIdx.x * BN;
    const int kBase = blockIdx.z * kPerZ;

    const int rowInChunk = lane >> 2;
    const int kOff8 = (lane & 3) * 8;

    const __hip_bfloat16* aSrc0 = A  + (size_t)(m0 + (wave * 2 + 0) * 16 + rowInChunk) * lda + kBase + kOff8;
    const __hip_bfloat16* aSrc1 = A  + (size_t)(m0 + (wave * 2 + 1) * 16 + rowInChunk) * lda + kBase + kOff8;
    const __hip_bfloat16* bSrc0 = Bm + (size_t)(n0 + (wave * 2 + 0) * 16 + rowInChunk) * ldb + kBase + kOff8;
    const __hip_bfloat16* bSrc1 = Bm + (size_t)(n0 + (wave * 2 + 1) * 16 + rowInChunk) * ldb + kBase + kOff8;

    const int wSlot = (((lane & 3) + ((lane >> 3) & 3)) & 3) * 8;
    const int ldsW0 = (wave * 2 + 0) * 512 + rowInChunk * 32 + wSlot;
    const int ldsW1 = ldsW0 + 512;

    const int rSlot = ((((lane >> 4) + (((lane & 15) >> 1) & 3)) & 3)) * 8;
    const int rRow  = lane & 15;

    floatx4 acc[4][4];
    const floatx4 zero4 = {0.f, 0.f, 0.f, 0.f};
    #pragma unroll
    for (int i = 0; i < 4; i++)
        #pragma unroll
        for (int j = 0; j < 4; j++) acc[i][j] = zero4;

    int4 aA0, aA1, bA0, bA1;
    int4 aB0, aB1, bB0, bB1;

    aA0 = *(const int4*)aSrc0; aA1 = *(const int4*)aSrc1;
    bA0 = *(const int4*)bSrc0; bA1 = *(const int4*)bSrc1;
    aSrc0 += BK; aSrc1 += BK; bSrc0 += BK; bSrc1 += BK;
    aB0 = *(const int4*)aSrc0; aB1 = *(const int4*)aSrc1;
    bB0 = *(const int4*)bSrc0; bB1 = *(const int4*)bSrc1;
    aSrc0 += BK; aSrc1 += BK; bSrc0 += BK; bSrc1 += BK;

    *(int4*)(&As[0][ldsW0]) = aA0;
    *(int4*)(&As[0][ldsW1]) = aA1;
    *(int4*)(&Bs[0][ldsW0]) = bA0;
    *(int4*)(&Bs[0][ldsW1]) = bA1;
    wg_barrier_lds();

    for (int kt = 0; kt < kIters; kt += 2) {
        const bool more = (kt + 2 < kIters);

        {
            bf16x8 af[4], bfr[4];
            #pragma unroll
            for (int mi = 0; mi < 4; mi++)
                af[mi] = *(const bf16x8*)(&As[0][(wi * 64 + mi * 16 + rRow) * BK + rSlot]);
            #pragma unroll
            for (int nj = 0; nj < 4; nj++)
                bfr[nj] = *(const bf16x8*)(&Bs[0][(wj * 64 + nj * 16 + rRow) * BK + rSlot]);

            if (more) {
                aA0 = *(const int4*)aSrc0; aA1 = *(const int4*)aSrc1;
                bA0 = *(const int4*)bSrc0; bA1 = *(const int4*)bSrc1;
                aSrc0 += BK; aSrc1 += BK; bSrc0 += BK; bSrc1 += BK;
            }
            *(int4*)(&As[1][ldsW0]) = aB0;
            *(int4*)(&As[1][ldsW1]) = aB1;
            *(int4*)(&Bs[1][ldsW0]) = bB0;
            *(int4*)(&Bs[1][ldsW1]) = bB1;

            #pragma unroll
            for (int mi = 0; mi < 4; mi++)
                #pragma unroll
                for (int nj = 0; nj < 4; nj++)
                    acc[mi][nj] = __builtin_amdgcn_mfma_f32_16x16x32_bf16(af[mi], bfr[nj], acc[mi][nj], 0, 0, 0);

            wg_barrier_lds();
        }

        {
            bf16x8 af[4], bfr[4];
            #pragma unroll
            for (int mi = 0; mi < 4; mi++)
                af[mi] = *(const bf16x8*)(&As[1][(wi * 64 + mi * 16 + rRow) * BK + rSlot]);
            #pragma unroll
            for (int nj = 0; nj < 4; nj++)
                bfr[nj] = *(const bf16x8*)(&Bs[1][(wj * 64 + nj * 16 + rRow) * BK + rSlot]);

            if (more) {
                aB0 = *(const int4*)aSrc0; aB1 = *(const int4*)aSrc1;
                bB0 = *(const int4*)bSrc0; bB1 = *(const int4*)bSrc1;
                aSrc0 += BK; aSrc1 += BK; bSrc0 += BK; bSrc1 += BK;
                *(int4*)(&As[0][ldsW0]) = aA0;
                *(int4*)(&As[0][ldsW1]) = aA1;
                *(int4*)(&Bs[0][ldsW0]) = bA0;
                *(int4*)(&Bs[0][ldsW1]) = bA1;
            }

            #pragma unroll
            for (int mi = 0; mi < 4; mi++)
                #pragma unroll
                for (int nj = 0; nj < 4; nj++)
                    acc[mi][nj] = __builtin_amdgcn_mfma_f32_16x16x32_bf16(af[mi], bfr[nj], acc[mi][nj], 0, 0, 0);

            wg_barrier_lds();
        }
    }

    #pragma unroll
    for (int mi = 0; mi < 4; mi++) {
        #pragma unroll
        for (int nj = 0; nj < 4; nj++) {
            #pragma unroll
            for (int r = 0; r < 4; r++) {
                const int row = m0 + wi * 64 + mi * 16 + (lane >> 4) * 4 + r;
                const int col = n0 + wj * 64 + nj * 16 + (lane & 15);
                const float v = acc[mi][nj][r];
                if (MODE == 1) {
                    if (row < NREAL) {
                        const int c = col & 31, b = col >> 5;
                        const float t = elu_f(v + bias[c]);
                        outH[(size_t)b * KFC + row * 32 + c] = __float2bfloat16(t);
                    }
                } else {
                    outF[(size_t)blockIdx.z * sliceStride + (size_t)row * ldc + col] = v;
                }
            }
        }
    }
}

// ---------------------------------------------------------------------------
// G3: 256x256 quadrant-per-phase GEMM with half-slot ring pipeline.
//
//   C[n][j] = sum_m Abf[n][m] * Tt[j][m].  K = 896 = 14 tiles of BK=64.
//
// Per phase ALL 8 waves compute ONE 128x128 C-quadrant (qm,qn) over the
// tile's full K=64, consuming exactly A-half qm (128x64) + B-half qn.
// Wave (vm,vn)=(w>>2,w&3) owns a 64x32 sub-block: 4mi x 2nj x 2kh = 16 MFMA.
// Phase order per tile: (0,0),(0,1),(1,0),(1,1).
//
// LDS: ring of 4 half-slots per matrix (Ah[4][128*64], Bh[4][128*64] =
// 128 KiB).  Half h of tile t -> slot (2t+h)&3.  Rotation swizzle within
// rows (slot(k>>3) = (k>>3 + row&7)&7): reads 2-way-free, staging via
// linear LDS dest + pre-swizzled per-lane global source (rule #21).
//
// Issue/wait LEDGER (per-wave, gloads; each half = 2 gloads):
//   issue:  t.p0: A1(t+1), B1(t+1), B0(t+1)   [slots freed by boundary bar]
//           t.p2: A0(t+2)                     [slot freed by mid-tile bar]
//   leads:  A0: 6 phases, B1: 5, A1: 6, B0: 4  (all >= 4)
//   waits:  boundary of t: vmcnt(2)  (youngest 2 = A0(t+1); forces all of
//           tile t's halves landed), last tile: vmcnt(0).  No other waits.
//   barriers: 2/tile — boundary (data visibility + slot reuse for p0
//           issues) and mid-tile (slot reuse for A0(t+2) vs A0(t) reads).
// ---------------------------------------------------------------------------
#define KT_G3 14

#define STAGE_A(tt, hh) do {                                                    \
    const int s_ = (2 * (tt) + (hh)) & 3;                                       \
    gload_lds16(aSrcH[hh][0] + (tt) * 64, &Ah[s_][(wave * 2 + 0) * 512]);       \
    gload_lds16(aSrcH[hh][1] + (tt) * 64, &Ah[s_][(wave * 2 + 1) * 512]);       \
} while (0)

#define STAGE_B(tt, hh) do {                                                    \
    const int s_ = (2 * (tt) + (hh)) & 3;                                       \
    gload_lds16(bSrcH[hh][0] + (tt) * 64, &Bh[s_][(wave * 2 + 0) * 512]);       \
    gload_lds16(bSrcH[hh][1] + (tt) * 64, &Bh[s_][(wave * 2 + 1) * 512]);       \
} while (0)

#define G3_PHASE(QM, QN, ISS)                                                   \
  {                                                                             \
    const int sA_ = (2 * t + (QM)) & 3;                                         \
    const int sB_ = (2 * t + (QN)) & 3;                                         \
    bf16x8 a0_[4], a1_[4], b0_[2], b1_[2];                                      \
    _Pragma("unroll")                                                           \
    for (int mi_ = 0; mi_ < 4; mi_++) {                                         \
      const int ro_ = aBase + mi_ * 1024;                                       \
      a0_[mi_] = *(const bf16x8*)(&Ah[sA_][ro_ + koff0]);                       \
      a1_[mi_] = *(const bf16x8*)(&Ah[sA_][ro_ + koff1]);                       \
    }                                                                           \
    _Pragma("unroll")                                                           \
    for (int nj_ = 0; nj_ < 2; nj_++) {                                         \
      const int ro_ = bBase + nj_ * 1024;                                       \
      b0_[nj_] = *(const bf16x8*)(&Bh[sB_][ro_ + koff0]);                       \
      b1_[nj_] = *(const bf16x8*)(&Bh[sB_][ro_ + koff1]);                       \
    }                                                                           \
    ISS                                                                         \
    lgkm0_fence();                                                              \
    __builtin_amdgcn_s_setprio(1);                                              \
    _Pragma("unroll")                                                           \
    for (int nj_ = 0; nj_ < 2; nj_++)                                           \
      _Pragma("unroll")                                                         \
      for (int mi_ = 0; mi_ < 4; mi_++)                                         \
        acc[(QM) * 2 + (QN)][mi_][nj_] = __builtin_amdgcn_mfma_f32_16x16x32_bf16( \
            a0_[mi_], b0_[nj_], acc[(QM) * 2 + (QN)][mi_][nj_], 0, 0, 0);       \
    _Pragma("unroll")                                                           \
    for (int nj_ = 0; nj_ < 2; nj_++)                                           \
      _Pragma("unroll")                                                         \
      for (int mi_ = 0; mi_ < 4; mi_++)                                         \
        acc[(QM) * 2 + (QN)][mi_][nj_] = __builtin_amdgcn_mfma_f32_16x16x32_bf16( \
            a1_[mi_], b1_[nj_], acc[(QM) * 2 + (QN)][mi_][nj_], 0, 0, 0);       \
    __builtin_amdgcn_s_setprio(0);                                              \
  }

__launch_bounds__(512, 2)
__global__ void gemm256_g3(const __hip_bfloat16* __restrict__ Ag,   // Abf [896][896]
                           const __hip_bfloat16* __restrict__ Bg,   // Tt  [32768][896]
                           __hip_bfloat16* __restrict__ outH,       // h2f
                           const float* __restrict__ bias)          // b2 [32]
{
    __shared__ __align__(16) __hip_bfloat16 Ah[4][128 * 64];
    __shared__ __align__(16) __hip_bfloat16 Bh[4][128 * 64];

    const int tid  = threadIdx.x;
    const int lane = tid & 63;
    const int wave = tid >> 6;
    const int vm = wave >> 2, vn = wave & 3;

    const int mR = blockIdx.y * 256;    // output rows (Abf rows; >=896 clamped+masked)
    const int nR = blockIdx.x * 256;    // output cols (Tt rows)

    // ---- read-side constants ----
    const int rRow = lane & 15;
    const int gHi  = lane >> 4;              // 0..3 (k-group within half-K)
    const int rot  = lane & 7;               // == (read row) & 7
    const int koff0 = (((gHi + rot) & 7) << 3);
    const int koff1 = ((((4 + gHi) + rot) & 7) << 3);
    const int aBase = (vm * 64 + rRow) * 64;
    const int bBase = (vn * 32 + rRow) * 64;

    // ---- staging constants (pre-swizzled global source, linear LDS dest) ----
    const int rowLoc = lane >> 3;                       // row within 8-row chunk
    const int gOff   = ((((lane & 7) - rowLoc) & 7) << 3);
    const __hip_bfloat16* aSrcH[2][2];
    const __hip_bfloat16* bSrcH[2][2];
    #pragma unroll
    for (int h = 0; h < 2; h++)
        #pragma unroll
        for (int j = 0; j < 2; j++) {
            int ra = mR + h * 128 + (wave * 2 + j) * 8 + rowLoc;
            if (ra > NPAD - 1) ra = NPAD - 1;   // clamp: garbage rows store-masked
            aSrcH[h][j] = Ag + (size_t)ra * NPAD + gOff;
            const int rb = nR + h * 128 + (wave * 2 + j) * 8 + rowLoc;
            bSrcH[h][j] = Bg + (size_t)rb * NPAD + gOff;
        }

    // per-thread bias values (col&31 = nj*16 + rRow)
    const float bias0 = bias[rRow];
    const float bias1 = bias[16 + rRow];

    floatx4 acc[4][4][2];
    const floatx4 zero4 = {0.f, 0.f, 0.f, 0.f};
    #pragma unroll
    for (int q = 0; q < 4; q++)
        #pragma unroll
        for (int i = 0; i < 4; i++)
            #pragma unroll
            for (int j = 0; j < 2; j++) acc[q][i][j] = zero4;

    // ---- prologue (ledger order: A0(0); A1,B1,B0(0); A0(1)) ----
    STAGE_A(0, 0);
    STAGE_A(0, 1); STAGE_B(0, 1); STAGE_B(0, 0);
    STAGE_A(1, 0);

    #pragma unroll 2
    for (int t = 0; t < KT_G3; ++t) {
        // boundary: counted wait (youngest 2 = A0(t+1) stay in flight)
        if (t == KT_G3 - 1) { asm volatile("s_waitcnt vmcnt(0)" ::: "memory"); }
        else                { asm volatile("s_waitcnt vmcnt(2)" ::: "memory"); }
        bar();

        G3_PHASE(0, 0, {
            if (t + 1 < KT_G3) { STAGE_A(t + 1, 1); STAGE_B(t + 1, 1); STAGE_B(t + 1, 0); }
        })
        G3_PHASE(0, 1, { })

        bar();   // mid-tile: all waves done reading A-half0(t)

        G3_PHASE(1, 0, {
            if (t + 2 < KT_G3) { STAGE_A(t + 2, 0); }
        })
        G3_PHASE(1, 1, { })
    }

    // ---- epilogue: C/D layout col=lane&15, row=(lane>>4)*4+reg (m89/m91) ----
    #pragma unroll
    for (int q = 0; q < 4; q++) {
        const int qm = q >> 1, qn = q & 1;
        #pragma unroll
        for (int mi = 0; mi < 4; mi++) {
            #pragma unroll
            for (int nj = 0; nj < 2; nj++) {
                #pragma unroll
                for (int r = 0; r < 4; r++) {
                    const int row = mR + qm * 128 + vm * 64 + mi * 16 + gHi * 4 + r;
                    if (row < NREAL) {
                        const int col = nR + qn * 128 + vn * 32 + nj * 16 + rRow;
                        const int c = col & 31, b = col >> 5;
                        const float bv = nj ? bias1 : bias0;
                        const float v = elu_f(acc[q][mi][nj][r] + bv);
                        outH[(size_t)b * KFC + row * 32 + c] = __float2bfloat16(v);
                    }
                }
            }
        }
    }
}

// ---------------------------------------------------------------------------
// Conversions / padding
// ---------------------------------------------------------------------------
__global__ void convX(const float* __restrict__ x, __hip_bfloat16* __restrict__ Xbf) {
    const int idx = blockIdx.x * 256 + threadIdx.x;
    if (idx >= BATCH * NPAD) return;
    const int m = idx % NPAD, b = idx / NPAD;
    const float v = (m < NREAL) ? x[(size_t)b * NREAL + m] : 0.f;
    Xbf[idx] = __float2bfloat16(v);
}

__global__ void convA(const float* __restrict__ a, __hip_bfloat16* __restrict__ Abf) {
    const int idx = blockIdx.x * 256 + threadIdx.x;
    if (idx >= NPAD * NPAD) return;
    const int m = idx % NPAD, n = idx / NPAD;
    const float v = (m < NREAL && n < NREAL) ? a[(size_t)n * NREAL + m] : 0.f;
    Abf[idx] = __float2bfloat16(v);
}

// wf1 [25088][512] fp32 -> Wt [512][25088] bf16 (LDS tile transpose)
__global__ void convW(const float* __restrict__ wf1, __hip_bfloat16* __restrict__ Wt) {
    __shared__ float tile[32][33];
    const int k0 = blockIdx.x * 32, h0 = blockIdx.y * 32;
    const int tx = threadIdx.x, ty = threadIdx.y;  // (32,8)
    #pragma unroll
    for (int i = 0; i < 4; i++)
        tile[ty * 4 + i][tx] = wf1[(size_t)(k0 + ty * 4 + i) * HDIM + h0 + tx];
    __syncthreads();
    #pragma unroll
    for (int i = 0; i < 4; i++)
        Wt[(size_t)(h0 + ty * 4 + i) * KFC + k0 + tx] = __float2bfloat16(tile[tx][ty * 4 + i]);
}

// ---------------------------------------------------------------------------
// Layer-1 fused pointwise
// ---------------------------------------------------------------------------
__global__ void layer1_fuse(const float* __restrict__ Ypart,
                            const float* __restrict__ w1, const float* __restrict__ b1,
                            const float* __restrict__ w2,
                            __hip_bfloat16* __restrict__ Tt)
{
    __shared__ __align__(16) float sW2[C1D * C2D];
    __shared__ float sw1[C1D], sb1[C1D];
    const int tid = threadIdx.x;                 // 128 threads
    for (int i = tid; i < C1D * C2D; i += 128) sW2[i] = w2[i];
    if (tid < C1D) { sw1[tid] = w1[tid]; sb1[tid] = b1[tid]; }
    __syncthreads();

    const int m = blockIdx.x * 128 + tid;        // 0..895
    const int b = blockIdx.y;
    float y = 0.f;
    #pragma unroll
    for (int z = 0; z < KS_G1; z++)
        y += Ypart[(size_t)z * (BATCH * NPAD) + (size_t)b * NPAD + m];

    float h[C1D];
    #pragma unroll
    for (int c1 = 0; c1 < C1D; c1++) h[c1] = elu_f(y * sw1[c1] + sb1[c1]);

    float4 t4[8];
    #pragma unroll
    for (int q = 0; q < 8; q++) t4[q] = make_float4(0.f, 0.f, 0.f, 0.f);
    #pragma unroll
    for (int c1 = 0; c1 < C1D; c1++) {
        const float hv = h[c1];
        const float4* row = (const float4*)(sW2 + c1 * C2D);
        #pragma unroll
        for (int q = 0; q < 8; q++) {
            const float4 w = row[q];
            t4[q].x += hv * w.x; t4[q].y += hv * w.y;
            t4[q].z += hv * w.z; t4[q].w += hv * w.w;
        }
    }
    const float* tf = (const float*)t4;
    #pragma unroll
    for (int c = 0; c < C2D; c++)
        Tt[((size_t)(b * 32 + c)) * NPAD + m] = __float2bfloat16(tf[c]);
}

// ---------------------------------------------------------------------------
// fc1 reduce + relu + fc2 + softmax, fused.
// ---------------------------------------------------------------------------
__global__ void fc2_softmax(const float* __restrict__ part, const float* __restrict__ bf1,
                            const float* __restrict__ wf2, const float* __restrict__ bf2,
                            float* __restrict__ out)
{
    __shared__ float sW[HDIM * NCLS];
    __shared__ float sb[NCLS];
    const int tid = threadIdx.x;                 // 256
    for (int i = tid; i < HDIM * NCLS; i += 256) sW[i] = wf2[i];
    if (tid < NCLS) sb[tid] = bf2[tid];
    __syncthreads();

    const int lane = tid & 63, wave = tid >> 6;
    const int b = blockIdx.x * 4 + wave;

    float acc[NCLS];
    #pragma unroll
    for (int c = 0; c < NCLS; c++) acc[c] = 0.f;
    #pragma unroll
    for (int q = 0; q < 8; q++) {
        const int h = q * 64 + lane;
        float hv = bf1[h];
        #pragma unroll
        for (int z = 0; z < KS_FC; z++)
            hv += part[(size_t)z * (BATCH * HDIM) + (size_t)b * HDIM + h];
        hv = hv > 0.f ? hv : 0.f;
        #pragma unroll
        for (int c = 0; c < NCLS; c++) acc[c] += hv * sW[h * NCLS + c];
    }
    #pragma unroll
    for (int c = 0; c < NCLS; c++) {
        #pragma unroll
        for (int off = 32; off >= 1; off >>= 1) acc[c] += __shfl_down(acc[c], off);
    }
    if (lane == 0) {
        float mx = -1e30f;
        #pragma unroll
        for (int c = 0; c < NCLS; c++) { acc[c] += sb[c]; mx = fmaxf(mx, acc[c]); }
        float e[NCLS], s = 0.f;
        #pragma unroll
        for (int c = 0; c < NCLS; c++) { e[c] = __expf(acc[c] - mx); s += e[c]; }
        const float inv = 1.f / s;
        #pragma unroll
        for (int c = 0; c < NCLS; c++) out[(size_t)b * NCLS + c] = e[c] * inv;
    }
}

// ---------------------------------------------------------------------------
// Workspace layout (peak ~113.5 MB) — unchanged
//   h2f   [0,          51380224)  bf16 1024x25088  (written G3, read G4)
//     Ypart [0, 25690112) f32 7x1024x896 — overlay, dead before G3 writes h2f
//   Tt    [51380224,  110100480)  bf16 32768x896   (dead after G3)
//     Wt   [51380224, 77070336)   bf16 512x25088 — overlay after G3
//     part [77070336, 106430464)  f32 14x1024x512 — overlay after G3
//   Abf   [110100480, 111706112)  bf16 896x896
//   Xbf   [111706112, 113541120)  bf16 1024x896    (dead after G1)
// ---------------------------------------------------------------------------
extern "C" void kernel_launch(void* const* d_in, const int* in_sizes, int n_in,
                              void* d_out, int out_size, void* d_ws, size_t ws_size,
                              hipStream_t stream)
{
    const float* x   = (const float*)d_in[0];
    const float* a   = (const float*)d_in[1];
    const float* w1  = (const float*)d_in[2];
    const float* b1  = (const float*)d_in[3];
    const float* w2  = (const float*)d_in[4];
    const float* b2  = (const float*)d_in[5];
    const float* wf1 = (const float*)d_in[6];
    const float* bf1 = (const float*)d_in[7];
    const float* wf2 = (const float*)d_in[8];
    const float* bf2 = (const float*)d_in[9];
    float* out = (float*)d_out;

    char* ws = (char*)d_ws;
    __hip_bfloat16* h2f  = (__hip_bfloat16*)(ws + 0);
    float*          Ypart= (float*)(ws + 0);                  // overlay (pre-G3)
    __hip_bfloat16* Tt   = (__hip_bfloat16*)(ws + 51380224);
    __hip_bfloat16* Wt   = (__hip_bfloat16*)(ws + 51380224);  // overlay (post-G3)
    float*          part = (float*)(ws + 77070336);           // overlay (post-G3)
    __hip_bfloat16* Abf  = (__hip_bfloat16*)(ws + 110100480);
    __hip_bfloat16* Xbf  = (__hip_bfloat16*)(ws + 111706112);

    convX<<<(BATCH * NPAD + 255) / 256, 256, 0, stream>>>(x, Xbf);
    convA<<<(NPAD * NPAD + 255) / 256, 256, 0, stream>>>(a, Abf);

    // G1: Ypart[z][b][n] partials of sum_m Xbf[b][m]*Abf[n][m]
    gemm_bt<2><<<dim3(NPAD / BN, BATCH / BM, KS_G1), 256, 0, stream>>>(
        Xbf, NPAD, Abf, NPAD, (NPAD / KS_G1) / BK, NPAD / KS_G1,
        (size_t)BATCH * NPAD, Ypart, NPAD, nullptr, nullptr);

    // layer-1 pointwise + @W2, transposed store
    layer1_fuse<<<dim3(NPAD / 128, BATCH), 128, 0, stream>>>(Ypart, w1, b1, w2, Tt);

    // G3: h2 = elu(A @ T + b2) — quadrant-per-phase 256^2 kernel
    gemm256_g3<<<dim3(BATCH * 32 / 256, 1024 / 256), 512, 0, stream>>>(Abf, Tt, h2f, b2);

    // transpose wf1 -> bf16 (into the now-dead Tt region)
    convW<<<dim3(KFC / 32, HDIM / 32), dim3(32, 8), 0, stream>>>(wf1, Wt);

    // G4: fc1 partials, split-K=14
    gemm_bt<2><<<dim3(HDIM / BN, BATCH / BM, KS_FC), 256, 0, stream>>>(
        h2f, KFC, Wt, KFC, (KFC / KS_FC) / BK, KFC / KS_FC,
        (size_t)BATCH * HDIM, part, HDIM, nullptr, nullptr);

    // fc1 reduce + relu + fc2 + softmax
    fc2_softmax<<<BATCH / 4, 256, 0, stream>>>(part, bf1, wf2, bf2, out);
}